// Round 9
// baseline (268.830 us; speedup 1.0000x reference)
//
#include <hip/hip_runtime.h>
#include <hip/hip_bf16.h>

#define N_NODES 50000
#define N_EDGES 800000
#define NBKT 196           // ceil(50000/256) buckets of 256 nodes
#define ACHUNK 4096        // edges per block in binning kernels
#define AB 196             // ceil(800000/4096) histogram blocks
#define CASTB 6250         // 50000*128/4 float4 chunks / 256 threads
#define MG 782             // ceil(50000/64) gemm row-tiles

typedef unsigned short u16;
typedef short v8s __attribute__((ext_vector_type(8)));
typedef float v4f __attribute__((ext_vector_type(4)));

__device__ __forceinline__ u16 f2bf(float f){
  union { float f; unsigned u; } x; x.f = f;
  unsigned u = x.u;
  return (u16)((u + 0x7FFFu + ((u >> 16) & 1u)) >> 16);   // RNE
}
__device__ __forceinline__ float lo_bf(unsigned u){
  union { unsigned u; float f; } x; x.u = u << 16; return x.f;
}
__device__ __forceinline__ float hi_bf(unsigned u){
  union { unsigned u; float f; } x; x.u = u & 0xffff0000u; return x.f;
}

// ---------------- fused prep: cast x->bf16, 3x weight transpose, A1 partial hists

__device__ __forceinline__ void wprep1(const float* __restrict__ Wl,
                                       const float* __restrict__ Wr,
                                       u16* __restrict__ WT, int N1, int idx){
  int n = idx >> 7, k = idx & 127;
  float v = (n < N1) ? Wl[k * N1 + n] : Wr[k * N1 + (n - N1)];
  WT[n * 128 + k] = f2bf(v);
}

__global__ __launch_bounds__(256) void k_prep_a1(const float* __restrict__ x,
                                                 u16* __restrict__ Xb,
                                                 const float* __restrict__ Wl1,
                                                 const float* __restrict__ Wr1,
                                                 const float* __restrict__ Wl2,
                                                 const float* __restrict__ Wr2,
                                                 const float* __restrict__ Wl3,
                                                 const float* __restrict__ Wr3,
                                                 u16* __restrict__ WT1,
                                                 u16* __restrict__ WT2,
                                                 u16* __restrict__ WT3,
                                                 const int* __restrict__ edges,
                                                 int* __restrict__ bpart){
  __shared__ int h[NBKT];
  int b = blockIdx.x, tid = threadIdx.x;
  if (b < CASTB){
    int i = b * 256 + tid;                       // exact: 6250*256 = 1.6M float4
    float4 v = ((const float4*)x)[i];
    ((ushort4*)Xb)[i] = make_ushort4(f2bf(v.x), f2bf(v.y), f2bf(v.z), f2bf(v.w));
  } else if (b < CASTB + 128){
    wprep1(Wl1, Wr1, WT1, 128, (b - CASTB) * 256 + tid);
  } else if (b < CASTB + 256){
    wprep1(Wl2, Wr2, WT2, 128, (b - CASTB - 128) * 256 + tid);
  } else if (b < CASTB + 320){
    wprep1(Wl3, Wr3, WT3, 64, (b - CASTB - 256) * 256 + tid);   // 64 blocks
  } else {
    int ab = b - (CASTB + 320);                  // 0..AB-1
    for (int i = tid; i < NBKT; i += 256) h[i] = 0;
    __syncthreads();
    int base = ab * ACHUNK;
    for (int i = tid; i < ACHUNK; i += 256){
      int j = base + i;
      if (j < N_EDGES) atomicAdd(&h[edges[N_EDGES + j] >> 8], 1);
    }
    __syncthreads();
    for (int i = tid; i < NBKT; i += 256) bpart[ab * NBKT + i] = h[i];
  }
}

// reduce partial hists + scan -> bbase (exclusive, +total), init bcur
__global__ __launch_bounds__(256) void k_scanb(const int* __restrict__ bpart,
                                               int* __restrict__ bbase,
                                               int* __restrict__ bcur){
  __shared__ int s[256];
  int tid = threadIdx.x;
  int v = 0;
  if (tid < NBKT){
    int a0 = 0, a1 = 0, a2 = 0, a3 = 0;
    int r = 0;
    for (; r + 4 <= AB; r += 4){
      a0 += bpart[(r    ) * NBKT + tid];
      a1 += bpart[(r + 1) * NBKT + tid];
      a2 += bpart[(r + 2) * NBKT + tid];
      a3 += bpart[(r + 3) * NBKT + tid];
    }
    for (; r < AB; ++r) a0 += bpart[r * NBKT + tid];
    v = (a0 + a1) + (a2 + a3);
  }
  s[tid] = v; __syncthreads();
  for (int d = 1; d < 256; d <<= 1){
    int t = (tid >= d) ? s[tid - d] : 0;
    __syncthreads();
    s[tid] += t;
    __syncthreads();
  }
  if (tid < NBKT){ bbase[tid] = s[tid] - v; bcur[tid] = s[tid] - v; }
  if (tid == NBKT - 1) bbase[NBKT] = s[tid];
}

// bucket-major scatter; pair packed as (src<<8) | (dst & 255)
__global__ __launch_bounds__(256) void kA2(const int* __restrict__ edges,
                                           int* __restrict__ bcur,
                                           unsigned* __restrict__ pairs){
  __shared__ int h[NBKT];
  int tid = threadIdx.x;
  for (int i = tid; i < NBKT; i += 256) h[i] = 0;
  __syncthreads();
  int base = blockIdx.x * ACHUNK;
  for (int i = tid; i < ACHUNK; i += 256){
    int j = base + i;
    if (j < N_EDGES) atomicAdd(&h[edges[N_EDGES + j] >> 8], 1);
  }
  __syncthreads();
  for (int i = tid; i < NBKT; i += 256)
    h[i] = h[i] ? atomicAdd(&bcur[i], h[i]) : 0;   // h becomes block-local cursor
  __syncthreads();
  for (int i = tid; i < ACHUNK; i += 256){
    int j = base + i;
    if (j < N_EDGES){
      int s = edges[j], d = edges[N_EDGES + j];
      int pos = atomicAdd(&h[d >> 8], 1);
      pairs[pos] = ((unsigned)s << 8) | (unsigned)(d & 255);
    }
  }
}

// ---------------- kB body (bucket counting sort) --------------------

__device__ __forceinline__ void kB_body(int bkt, int tid,
                                        const unsigned* __restrict__ pairs,
                                        const int* __restrict__ bbase,
                                        int* __restrict__ off,
                                        int* __restrict__ deg,
                                        float* __restrict__ invdeg,
                                        int* __restrict__ cols,
                                        int* h, int* s, int* cur){
  int base = bbase[bkt], cnt = bbase[bkt + 1] - base;
  int nodeBase = bkt << 8;

  h[tid] = 0; __syncthreads();
  for (int i = tid; i < cnt; i += 256){
    unsigned p = pairs[base + i];
    atomicAdd(&h[p & 255u], 1);
  }
  __syncthreads();
  int v = h[tid];
  s[tid] = v; __syncthreads();
  for (int d = 1; d < 256; d <<= 1){
    int t = (tid >= d) ? s[tid - d] : 0;
    __syncthreads();
    s[tid] += t;
    __syncthreads();
  }
  int excl = s[tid] - v;
  int node = nodeBase + tid;
  if (node < N_NODES){
    off[node] = base + excl;
    deg[node] = v;
    invdeg[node] = 1.0f / (float)(v > 1 ? v : 1);
  }
  cur[tid] = base + excl;
  __syncthreads();
  for (int i = tid; i < cnt; i += 256){
    unsigned p = pairs[base + i];
    int pos = atomicAdd(&cur[p & 255u], 1);
    cols[pos] = (int)(p >> 8);
  }
}

// ---------------- 256-thread GEMM (Bs staged in LDS, R7 form) ------------------
// XLb = bf16(A@Wl + b), XR = bf16(A@Wr). WT rows [0,N1)=Wl^T, [N1,2N1)=Wr^T.

__device__ __forceinline__ void gemm_inner_lds(int rowBase, int tid,
                                               const u16* __restrict__ WT,
                                               const float* __restrict__ bias,
                                               u16* __restrict__ XLb,
                                               u16* __restrict__ XR, int N1,
                                               const u16* As, u16* Bs){
  const int lane = tid & 63, wave = tid >> 6;
  const int quad = lane >> 4, l15 = lane & 15;
  const int wm = wave & 1, wn = wave >> 1;
  const int nph = N1 >> 5;                       // (2*N1)/64 phases

  for (int p = 0; p < nph; ++p){
    int colBase = p * 64;
    #pragma unroll
    for (int it = 0; it < 4; ++it){
      int chunk = tid + it * 256;
      int r = chunk >> 4, cseg = chunk & 15;
      ((uint4*)Bs)[r * 17 + cseg] = ((const uint4*)(WT + (size_t)(colBase + r) * 128))[cseg];
    }
    __syncthreads();

    v4f acc[2][2] = {};
    #pragma unroll
    for (int kt = 0; kt < 4; ++kt){
      int ko = kt * 32 + quad * 8;
      v8s a0 = *(const v8s*)&As[(wm * 32 + l15) * 136 + ko];
      v8s a1 = *(const v8s*)&As[(wm * 32 + 16 + l15) * 136 + ko];
      v8s b0 = *(const v8s*)&Bs[(wn * 32 + l15) * 136 + ko];
      v8s b1 = *(const v8s*)&Bs[(wn * 32 + 16 + l15) * 136 + ko];
      acc[0][0] = __builtin_amdgcn_mfma_f32_16x16x32_bf16(a0, b0, acc[0][0], 0, 0, 0);
      acc[0][1] = __builtin_amdgcn_mfma_f32_16x16x32_bf16(a0, b1, acc[0][1], 0, 0, 0);
      acc[1][0] = __builtin_amdgcn_mfma_f32_16x16x32_bf16(a1, b0, acc[1][0], 0, 0, 0);
      acc[1][1] = __builtin_amdgcn_mfma_f32_16x16x32_bf16(a1, b1, acc[1][1], 0, 0, 0);
    }

    #pragma unroll
    for (int mi = 0; mi < 2; ++mi)
      #pragma unroll
      for (int ni = 0; ni < 2; ++ni)
        #pragma unroll
        for (int r = 0; r < 4; ++r){
          int grow = rowBase + wm * 32 + mi * 16 + quad * 4 + r;
          int gcol = colBase + wn * 32 + ni * 16 + l15;
          if (grow < N_NODES){
            float v = acc[mi][ni][r];
            if (gcol < N1) XLb[(size_t)grow * N1 + gcol] = f2bf(v + bias[gcol]);
            else           XR[(size_t)grow * N1 + (gcol - N1)] = f2bf(v);
          }
        }
    __syncthreads();
  }
}

// kernel 4: bucket counting sort (blocks 0..NBKT) + layer-1 GEMM (rest)
__global__ __launch_bounds__(256) void k_kb_gemm(const unsigned* __restrict__ pairs,
                                                 const int* __restrict__ bbase,
                                                 int* __restrict__ off,
                                                 int* __restrict__ deg,
                                                 float* __restrict__ invdeg,
                                                 int* __restrict__ cols,
                                                 const u16* __restrict__ A,
                                                 const u16* __restrict__ WT,
                                                 const float* __restrict__ bias,
                                                 u16* __restrict__ XLb,
                                                 u16* __restrict__ XR){
  __shared__ u16 As[64 * 136];
  __shared__ u16 Bs[64 * 136];
  int tid = threadIdx.x;
  if (blockIdx.x < NBKT){
    int* h = (int*)As;               // 3 KB aliased into As
    kB_body(blockIdx.x, tid, pairs, bbase, off, deg, invdeg, cols,
            h, h + 256, h + 512);
  } else {
    const int rowBase = (blockIdx.x - NBKT) * 64;
    #pragma unroll
    for (int it = 0; it < 4; ++it){
      int chunk = tid + it * 256;
      int r = chunk >> 4, cseg = chunk & 15;
      int gr = rowBase + r;
      uint4 va = make_uint4(0u, 0u, 0u, 0u);
      if (gr < N_NODES) va = ((const uint4*)(A + (size_t)gr * 128))[cseg];
      ((uint4*)As)[r * 17 + cseg] = va;
    }
    __syncthreads();
    gemm_inner_lds(rowBase, tid, WT, bias, XLb, XR, 128, As, Bs);
  }
}

// ---------------- per-node aggregate (128-wide, relu, bf16 out as uint4) -------

__device__ __forceinline__ uint4 agg_node128(int node, int f,
                                             const int* __restrict__ off,
                                             const int* __restrict__ deg,
                                             const float* __restrict__ invdeg,
                                             const int* __restrict__ cols,
                                             const u16* __restrict__ XLb,
                                             const u16* __restrict__ XR){
  int start = off[node], cnt = deg[node];
  float inv = invdeg[node];
  const uint4* __restrict__ XR4 = (const uint4*)XR;   // row = 16 uint4
  const int* __restrict__ cb = cols + start;

  float2 a0 = make_float2(0.f, 0.f), a1 = a0, a2 = a0, a3 = a0;
  auto accum = [&](uint4 u){
    a0.x += lo_bf(u.x); a0.y += hi_bf(u.x);
    a1.x += lo_bf(u.y); a1.y += hi_bf(u.y);
    a2.x += lo_bf(u.z); a2.y += hi_bf(u.z);
    a3.x += lo_bf(u.w); a3.y += hi_bf(u.w);
  };

  int e = 0;
  int nfull = cnt & ~7;
  for (; e < nfull; e += 8){
    int s[8];
    #pragma unroll
    for (int j = 0; j < 8; ++j) s[j] = cb[e + j];
    uint4 u[8];
    #pragma unroll
    for (int j = 0; j < 8; ++j) u[j] = XR4[(size_t)s[j] * 16 + f];
    #pragma unroll
    for (int j = 0; j < 8; ++j) accum(u[j]);
  }
  if (e < cnt){                                 // masked 8-granule tail (<=1 iter)
    int last = cnt - 1;
    int s[8];
    #pragma unroll
    for (int j = 0; j < 8; ++j){
      int i = e + j;
      s[j] = cb[i < last ? i : last];
    }
    uint4 u[8];
    #pragma unroll
    for (int j = 0; j < 8; ++j) u[j] = XR4[(size_t)s[j] * 16 + f];
    #pragma unroll
    for (int j = 0; j < 8; ++j){
      if (e + j > last) u[j] = make_uint4(0u, 0u, 0u, 0u);
      accum(u[j]);
    }
  }

  uint4 xl = ((const uint4*)XLb)[(size_t)node * 16 + f];
  float o0 = lo_bf(xl.x) + inv * a0.x, o1 = hi_bf(xl.x) + inv * a0.y;
  float o2 = lo_bf(xl.y) + inv * a1.x, o3 = hi_bf(xl.y) + inv * a1.y;
  float o4 = lo_bf(xl.z) + inv * a2.x, o5 = hi_bf(xl.z) + inv * a2.y;
  float o6 = lo_bf(xl.w) + inv * a3.x, o7 = hi_bf(xl.w) + inv * a3.y;
  o0 = fmaxf(o0, 0.f); o1 = fmaxf(o1, 0.f); o2 = fmaxf(o2, 0.f); o3 = fmaxf(o3, 0.f);
  o4 = fmaxf(o4, 0.f); o5 = fmaxf(o5, 0.f); o6 = fmaxf(o6, 0.f); o7 = fmaxf(o7, 0.f);
  uint4 ov;
  ov.x = (unsigned)f2bf(o0) | ((unsigned)f2bf(o1) << 16);
  ov.y = (unsigned)f2bf(o2) | ((unsigned)f2bf(o3) << 16);
  ov.z = (unsigned)f2bf(o4) | ((unsigned)f2bf(o5) << 16);
  ov.w = (unsigned)f2bf(o6) | ((unsigned)f2bf(o7) << 16);
  return ov;
}

// ---------------- fused agg(layer l) + GEMM(layer l+1), 512 threads ------------
// 8 waves: agg = 32 quarter-waves x 2 passes -> 64 rows into As; GEMM covers
// 128 cols/phase (wm=wave&1 rows, wn=wave>>1 cols), B direct from global (L2-hot).

__global__ __launch_bounds__(512, 6) void k_aggemm(const int* __restrict__ off,
                                                   const int* __restrict__ deg,
                                                   const float* __restrict__ invdeg,
                                                   const int* __restrict__ cols,
                                                   const u16* __restrict__ XLb_in,
                                                   const u16* __restrict__ XR_in,
                                                   const u16* __restrict__ WT,
                                                   const float* __restrict__ bias,
                                                   u16* __restrict__ XLb_out,
                                                   u16* __restrict__ XR_out,
                                                   int N1_out){
  __shared__ u16 As[64 * 136];       // 17.4 KB
  int tid = threadIdx.x;
  int qq = tid >> 4, f = tid & 15;   // 32 quarter-waves
  int rowBase = blockIdx.x * 64;

  #pragma unroll
  for (int pass = 0; pass < 2; ++pass){
    int lr = pass * 32 + qq;                    // local row 0..63
    int node = rowBase + lr;
    uint4 ov = make_uint4(0u, 0u, 0u, 0u);
    if (node < N_NODES)
      ov = agg_node128(node, f, off, deg, invdeg, cols, XLb_in, XR_in);
    ((uint4*)As)[lr * 17 + f] = ov;
  }
  __syncthreads();

  const int lane = tid & 63, wave = tid >> 6;   // 8 waves
  const int quad = lane >> 4, l15 = lane & 15;
  const int wm = wave & 1, wn = wave >> 1;      // wn in 0..3 -> 128 cols/phase
  const int nph = N1_out >> 6;                  // 2*N1/128 phases (2 or 1)

  for (int p = 0; p < nph; ++p){
    int colBase = p * 128;
    const u16* __restrict__ brow0 = WT + (size_t)(colBase + wn * 32 + l15) * 128;
    const u16* __restrict__ brow1 = brow0 + 16 * 128;

    v4f acc[2][2] = {};
    #pragma unroll
    for (int kt = 0; kt < 4; ++kt){
      int ko = kt * 32 + quad * 8;
      v8s a0 = *(const v8s*)&As[(wm * 32 + l15) * 136 + ko];
      v8s a1 = *(const v8s*)&As[(wm * 32 + 16 + l15) * 136 + ko];
      v8s b0 = *(const v8s*)&brow0[ko];          // global_load_dwordx4, L2-hot
      v8s b1 = *(const v8s*)&brow1[ko];
      acc[0][0] = __builtin_amdgcn_mfma_f32_16x16x32_bf16(a0, b0, acc[0][0], 0, 0, 0);
      acc[0][1] = __builtin_amdgcn_mfma_f32_16x16x32_bf16(a0, b1, acc[0][1], 0, 0, 0);
      acc[1][0] = __builtin_amdgcn_mfma_f32_16x16x32_bf16(a1, b0, acc[1][0], 0, 0, 0);
      acc[1][1] = __builtin_amdgcn_mfma_f32_16x16x32_bf16(a1, b1, acc[1][1], 0, 0, 0);
    }

    #pragma unroll
    for (int mi = 0; mi < 2; ++mi)
      #pragma unroll
      for (int ni = 0; ni < 2; ++ni)
        #pragma unroll
        for (int r = 0; r < 4; ++r){
          int grow = rowBase + wm * 32 + mi * 16 + quad * 4 + r;
          int gcol = colBase + wn * 32 + ni * 16 + l15;
          if (grow < N_NODES){
            float v = acc[mi][ni][r];
            if (gcol < N1_out) XLb_out[(size_t)grow * N1_out + gcol] = f2bf(v + bias[gcol]);
            else               XR_out[(size_t)grow * N1_out + (gcol - N1_out)] = f2bf(v);
          }
        }
  }
}

// ---------------- final aggregate (64-wide, fp32 out) --------------------------
__global__ __launch_bounds__(256) void k_agg64(const int* __restrict__ off,
                                               const int* __restrict__ deg,
                                               const float* __restrict__ invdeg,
                                               const int* __restrict__ cols,
                                               const u16* __restrict__ XLb,
                                               const u16* __restrict__ XR,
                                               float* __restrict__ out){
  int tid = threadIdx.x;
  int oo = tid >> 3, f = tid & 7;
  int node = blockIdx.x * 32 + oo;
  if (node >= N_NODES) return;
  int start = off[node], cnt = deg[node];
  float inv = invdeg[node];
  const uint4* __restrict__ XR4 = (const uint4*)XR;   // row = 8 uint4
  const int* __restrict__ cb = cols + start;

  float2 a0 = make_float2(0.f, 0.f), a1 = a0, a2 = a0, a3 = a0;
  auto accum = [&](uint4 u){
    a0.x += lo_bf(u.x); a0.y += hi_bf(u.x);
    a1.x += lo_bf(u.y); a1.y += hi_bf(u.y);
    a2.x += lo_bf(u.z); a2.y += hi_bf(u.z);
    a3.x += lo_bf(u.w); a3.y += hi_bf(u.w);
  };

  int e = 0;
  int nfull = cnt & ~7;
  for (; e < nfull; e += 8){
    int s[8];
    #pragma unroll
    for (int j = 0; j < 8; ++j) s[j] = cb[e + j];
    uint4 u[8];
    #pragma unroll
    for (int j = 0; j < 8; ++j) u[j] = XR4[(size_t)s[j] * 8 + f];
    #pragma unroll
    for (int j = 0; j < 8; ++j) accum(u[j]);
  }
  if (e < cnt){
    int last = cnt - 1;
    int s[8];
    #pragma unroll
    for (int j = 0; j < 8; ++j){
      int i = e + j;
      s[j] = cb[i < last ? i : last];
    }
    uint4 u[8];
    #pragma unroll
    for (int j = 0; j < 8; ++j) u[j] = XR4[(size_t)s[j] * 8 + f];
    #pragma unroll
    for (int j = 0; j < 8; ++j){
      if (e + j > last) u[j] = make_uint4(0u, 0u, 0u, 0u);
      accum(u[j]);
    }
  }

  uint4 xl = ((const uint4*)XLb)[(size_t)node * 8 + f];
  float4 oa, ob;
  oa.x = lo_bf(xl.x) + inv * a0.x; oa.y = hi_bf(xl.x) + inv * a0.y;
  oa.z = lo_bf(xl.y) + inv * a1.x; oa.w = hi_bf(xl.y) + inv * a1.y;
  ob.x = lo_bf(xl.z) + inv * a2.x; ob.y = hi_bf(xl.z) + inv * a2.y;
  ob.z = lo_bf(xl.w) + inv * a3.x; ob.w = hi_bf(xl.w) + inv * a3.y;
  ((float4*)out)[(size_t)node * 16 + 2 * f]     = oa;
  ((float4*)out)[(size_t)node * 16 + 2 * f + 1] = ob;
}

// ---------------- launch ----------------

extern "C" void kernel_launch(void* const* d_in, const int* in_sizes, int n_in,
                              void* d_out, int out_size, void* d_ws, size_t ws_size,
                              hipStream_t stream) {
  const float* x     = (const float*)d_in[0];
  const int*   edges = (const int*)  d_in[1];
  const float* Wl1 = (const float*)d_in[2];
  const float* Wr1 = (const float*)d_in[3];
  const float* b1  = (const float*)d_in[4];
  const float* Wl2 = (const float*)d_in[5];
  const float* Wr2 = (const float*)d_in[6];
  const float* b2  = (const float*)d_in[7];
  const float* Wl3 = (const float*)d_in[8];
  const float* Wr3 = (const float*)d_in[9];
  const float* b3  = (const float*)d_in[10];

  char* ws = (char*)d_ws;
  size_t o = 0;
  auto alloc = [&](size_t bytes) -> void* {
    void* p = ws + o;
    o += (bytes + 255) & ~(size_t)255;
    return p;
  };
  int*      deg    = (int*)     alloc(N_NODES * 4);
  int*      off    = (int*)     alloc(N_NODES * 4);
  float*    invdeg = (float*)   alloc(N_NODES * 4);
  int*      bpart  = (int*)     alloc((size_t)AB * NBKT * 4);
  int*      bbase  = (int*)     alloc((NBKT + 1) * 4);
  int*      bcur   = (int*)     alloc(NBKT * 4);
  unsigned* pairs  = (unsigned*)alloc((size_t)N_EDGES * 4);
  int*      cols   = (int*)     alloc(N_EDGES * 4);
  u16*      Xb     = (u16*)     alloc((size_t)N_NODES * 128 * 2);
  u16*      XLbA   = (u16*)     alloc((size_t)N_NODES * 128 * 2);
  u16*      XRbA   = (u16*)     alloc((size_t)N_NODES * 128 * 2);
  u16*      XLbB   = (u16*)     alloc((size_t)N_NODES * 128 * 2);
  u16*      XRbB   = (u16*)     alloc((size_t)N_NODES * 128 * 2);
  u16*      WT1    = (u16*)     alloc(256 * 128 * 2);
  u16*      WT2    = (u16*)     alloc(256 * 128 * 2);
  u16*      WT3    = (u16*)     alloc(128 * 128 * 2);

  // 1. prep (cast + wprep x3) + A1 partial histograms
  k_prep_a1<<<CASTB + 320 + AB, 256, 0, stream>>>(x, Xb, Wl1, Wr1, Wl2, Wr2,
                                                  Wl3, Wr3, WT1, WT2, WT3,
                                                  edges, bpart);
  // 2. reduce + scan bucket counts
  k_scanb<<<1, 256, 0, stream>>>(bpart, bbase, bcur);
  // 3. bucket-major pair scatter (packed u32 pairs)
  kA2<<<AB, 256, 0, stream>>>(edges, bcur, pairs);
  // 4. bucket counting sort (CSR) + layer-1 GEMM (Bs-staged, R7 form)
  k_kb_gemm<<<NBKT + MG, 256, 0, stream>>>(pairs, bbase, off, deg, invdeg, cols,
                                           Xb, WT1, b1, XLbA, XRbA);
  // 5. agg1 + gemm2 fused, 512 threads (24 waves/CU)
  k_aggemm<<<MG, 512, 0, stream>>>(off, deg, invdeg, cols, XLbA, XRbA,
                                   WT2, b2, XLbB, XRbB, 128);
  // 6. agg2 + gemm3 fused
  k_aggemm<<<MG, 512, 0, stream>>>(off, deg, invdeg, cols, XLbB, XRbB,
                                   WT3, b3, XLbA, XRbA, 64);
  // 7. final aggregate (fp32 out)
  k_agg64<<<(N_NODES + 31) / 32, 256, 0, stream>>>(off, deg, invdeg, cols,
                                                   XLbA, XRbA, (float*)d_out);
}

// Round 10
// 235.085 us; speedup vs baseline: 1.1435x; 1.1435x over previous
//
#include <hip/hip_runtime.h>
#include <hip/hip_bf16.h>

#define N_NODES 50000
#define N_EDGES 800000
#define NBKT 196           // ceil(50000/256) buckets of 256 nodes
#define ACHUNK 4096        // edges per block in binning kernels
#define AB 196             // ceil(800000/4096) histogram blocks
#define CASTB 6250         // 50000*128/4 float4 chunks / 256 threads
#define MG 782             // ceil(50000/64) gemm row-tiles
#define MG32 1563          // ceil(50000/32) aggemm row-tiles

typedef unsigned short u16;
typedef short v8s __attribute__((ext_vector_type(8)));
typedef float v4f __attribute__((ext_vector_type(4)));

__device__ __forceinline__ u16 f2bf(float f){
  union { float f; unsigned u; } x; x.f = f;
  unsigned u = x.u;
  return (u16)((u + 0x7FFFu + ((u >> 16) & 1u)) >> 16);   // RNE
}
__device__ __forceinline__ float lo_bf(unsigned u){
  union { unsigned u; float f; } x; x.u = u << 16; return x.f;
}
__device__ __forceinline__ float hi_bf(unsigned u){
  union { unsigned u; float f; } x; x.u = u & 0xffff0000u; return x.f;
}

// ---------------- fused prep: cast x->bf16, 3x weight transpose, A1 partial hists

__device__ __forceinline__ void wprep1(const float* __restrict__ Wl,
                                       const float* __restrict__ Wr,
                                       u16* __restrict__ WT, int N1, int idx){
  int n = idx >> 7, k = idx & 127;
  float v = (n < N1) ? Wl[k * N1 + n] : Wr[k * N1 + (n - N1)];
  WT[n * 128 + k] = f2bf(v);
}

__global__ __launch_bounds__(256) void k_prep_a1(const float* __restrict__ x,
                                                 u16* __restrict__ Xb,
                                                 const float* __restrict__ Wl1,
                                                 const float* __restrict__ Wr1,
                                                 const float* __restrict__ Wl2,
                                                 const float* __restrict__ Wr2,
                                                 const float* __restrict__ Wl3,
                                                 const float* __restrict__ Wr3,
                                                 u16* __restrict__ WT1,
                                                 u16* __restrict__ WT2,
                                                 u16* __restrict__ WT3,
                                                 const int* __restrict__ edges,
                                                 int* __restrict__ bpart){
  __shared__ int h[NBKT];
  int b = blockIdx.x, tid = threadIdx.x;
  if (b < CASTB){
    int i = b * 256 + tid;                       // exact: 6250*256 = 1.6M float4
    float4 v = ((const float4*)x)[i];
    ((ushort4*)Xb)[i] = make_ushort4(f2bf(v.x), f2bf(v.y), f2bf(v.z), f2bf(v.w));
  } else if (b < CASTB + 128){
    wprep1(Wl1, Wr1, WT1, 128, (b - CASTB) * 256 + tid);
  } else if (b < CASTB + 256){
    wprep1(Wl2, Wr2, WT2, 128, (b - CASTB - 128) * 256 + tid);
  } else if (b < CASTB + 320){
    wprep1(Wl3, Wr3, WT3, 64, (b - CASTB - 256) * 256 + tid);   // 64 blocks
  } else {
    int ab = b - (CASTB + 320);                  // 0..AB-1
    for (int i = tid; i < NBKT; i += 256) h[i] = 0;
    __syncthreads();
    int base = ab * ACHUNK;
    for (int i = tid; i < ACHUNK; i += 256){
      int j = base + i;
      if (j < N_EDGES) atomicAdd(&h[edges[N_EDGES + j] >> 8], 1);
    }
    __syncthreads();
    for (int i = tid; i < NBKT; i += 256) bpart[ab * NBKT + i] = h[i];
  }
}

// reduce partial hists + scan -> bbase (exclusive, +total), init bcur
__global__ __launch_bounds__(256) void k_scanb(const int* __restrict__ bpart,
                                               int* __restrict__ bbase,
                                               int* __restrict__ bcur){
  __shared__ int s[256];
  int tid = threadIdx.x;
  int v = 0;
  if (tid < NBKT){
    int a0 = 0, a1 = 0, a2 = 0, a3 = 0;
    int r = 0;
    for (; r + 4 <= AB; r += 4){
      a0 += bpart[(r    ) * NBKT + tid];
      a1 += bpart[(r + 1) * NBKT + tid];
      a2 += bpart[(r + 2) * NBKT + tid];
      a3 += bpart[(r + 3) * NBKT + tid];
    }
    for (; r < AB; ++r) a0 += bpart[r * NBKT + tid];
    v = (a0 + a1) + (a2 + a3);
  }
  s[tid] = v; __syncthreads();
  for (int d = 1; d < 256; d <<= 1){
    int t = (tid >= d) ? s[tid - d] : 0;
    __syncthreads();
    s[tid] += t;
    __syncthreads();
  }
  if (tid < NBKT){ bbase[tid] = s[tid] - v; bcur[tid] = s[tid] - v; }
  if (tid == NBKT - 1) bbase[NBKT] = s[tid];
}

// bucket-major scatter; pair packed as (src<<8) | (dst & 255)
__global__ __launch_bounds__(256) void kA2(const int* __restrict__ edges,
                                           int* __restrict__ bcur,
                                           unsigned* __restrict__ pairs){
  __shared__ int h[NBKT];
  int tid = threadIdx.x;
  for (int i = tid; i < NBKT; i += 256) h[i] = 0;
  __syncthreads();
  int base = blockIdx.x * ACHUNK;
  for (int i = tid; i < ACHUNK; i += 256){
    int j = base + i;
    if (j < N_EDGES) atomicAdd(&h[edges[N_EDGES + j] >> 8], 1);
  }
  __syncthreads();
  for (int i = tid; i < NBKT; i += 256)
    h[i] = h[i] ? atomicAdd(&bcur[i], h[i]) : 0;   // h becomes block-local cursor
  __syncthreads();
  for (int i = tid; i < ACHUNK; i += 256){
    int j = base + i;
    if (j < N_EDGES){
      int s = edges[j], d = edges[N_EDGES + j];
      int pos = atomicAdd(&h[d >> 8], 1);
      pairs[pos] = ((unsigned)s << 8) | (unsigned)(d & 255);
    }
  }
}

// ---------------- kB body (bucket counting sort) --------------------

__device__ __forceinline__ void kB_body(int bkt, int tid,
                                        const unsigned* __restrict__ pairs,
                                        const int* __restrict__ bbase,
                                        int* __restrict__ off,
                                        int* __restrict__ deg,
                                        float* __restrict__ invdeg,
                                        int* __restrict__ cols,
                                        int* h, int* s, int* cur){
  int base = bbase[bkt], cnt = bbase[bkt + 1] - base;
  int nodeBase = bkt << 8;

  h[tid] = 0; __syncthreads();
  for (int i = tid; i < cnt; i += 256){
    unsigned p = pairs[base + i];
    atomicAdd(&h[p & 255u], 1);
  }
  __syncthreads();
  int v = h[tid];
  s[tid] = v; __syncthreads();
  for (int d = 1; d < 256; d <<= 1){
    int t = (tid >= d) ? s[tid - d] : 0;
    __syncthreads();
    s[tid] += t;
    __syncthreads();
  }
  int excl = s[tid] - v;
  int node = nodeBase + tid;
  if (node < N_NODES){
    off[node] = base + excl;
    deg[node] = v;
    invdeg[node] = 1.0f / (float)(v > 1 ? v : 1);
  }
  cur[tid] = base + excl;
  __syncthreads();
  for (int i = tid; i < cnt; i += 256){
    unsigned p = pairs[base + i];
    int pos = atomicAdd(&cur[p & 255u], 1);
    cols[pos] = (int)(p >> 8);
  }
}

// ---------------- 64-row GEMM inner (Bs staged in LDS) — R7 form ---------------
// XLb = bf16(A@Wl + b), XR = bf16(A@Wr). WT rows [0,N1)=Wl^T, [N1,2N1)=Wr^T.

__device__ __forceinline__ void gemm_inner_lds(int rowBase, int tid,
                                               const u16* __restrict__ WT,
                                               const float* __restrict__ bias,
                                               u16* __restrict__ XLb,
                                               u16* __restrict__ XR, int N1,
                                               const u16* As, u16* Bs){
  const int lane = tid & 63, wave = tid >> 6;
  const int quad = lane >> 4, l15 = lane & 15;
  const int wm = wave & 1, wn = wave >> 1;
  const int nph = N1 >> 5;                       // (2*N1)/64 phases

  for (int p = 0; p < nph; ++p){
    int colBase = p * 64;
    #pragma unroll
    for (int it = 0; it < 4; ++it){
      int chunk = tid + it * 256;
      int r = chunk >> 4, cseg = chunk & 15;
      ((uint4*)Bs)[r * 17 + cseg] = ((const uint4*)(WT + (size_t)(colBase + r) * 128))[cseg];
    }
    __syncthreads();

    v4f acc[2][2] = {};
    #pragma unroll
    for (int kt = 0; kt < 4; ++kt){
      int ko = kt * 32 + quad * 8;
      v8s a0 = *(const v8s*)&As[(wm * 32 + l15) * 136 + ko];
      v8s a1 = *(const v8s*)&As[(wm * 32 + 16 + l15) * 136 + ko];
      v8s b0 = *(const v8s*)&Bs[(wn * 32 + l15) * 136 + ko];
      v8s b1 = *(const v8s*)&Bs[(wn * 32 + 16 + l15) * 136 + ko];
      acc[0][0] = __builtin_amdgcn_mfma_f32_16x16x32_bf16(a0, b0, acc[0][0], 0, 0, 0);
      acc[0][1] = __builtin_amdgcn_mfma_f32_16x16x32_bf16(a0, b1, acc[0][1], 0, 0, 0);
      acc[1][0] = __builtin_amdgcn_mfma_f32_16x16x32_bf16(a1, b0, acc[1][0], 0, 0, 0);
      acc[1][1] = __builtin_amdgcn_mfma_f32_16x16x32_bf16(a1, b1, acc[1][1], 0, 0, 0);
    }

    #pragma unroll
    for (int mi = 0; mi < 2; ++mi)
      #pragma unroll
      for (int ni = 0; ni < 2; ++ni)
        #pragma unroll
        for (int r = 0; r < 4; ++r){
          int grow = rowBase + wm * 32 + mi * 16 + quad * 4 + r;
          int gcol = colBase + wn * 32 + ni * 16 + l15;
          if (grow < N_NODES){
            float v = acc[mi][ni][r];
            if (gcol < N1) XLb[(size_t)grow * N1 + gcol] = f2bf(v + bias[gcol]);
            else           XR[(size_t)grow * N1 + (gcol - N1)] = f2bf(v);
          }
        }
    __syncthreads();
  }
}

// kernel 4: bucket counting sort (blocks 0..NBKT) + layer-1 GEMM (rest)
__global__ __launch_bounds__(256) void k_kb_gemm(const unsigned* __restrict__ pairs,
                                                 const int* __restrict__ bbase,
                                                 int* __restrict__ off,
                                                 int* __restrict__ deg,
                                                 float* __restrict__ invdeg,
                                                 int* __restrict__ cols,
                                                 const u16* __restrict__ A,
                                                 const u16* __restrict__ WT,
                                                 const float* __restrict__ bias,
                                                 u16* __restrict__ XLb,
                                                 u16* __restrict__ XR){
  __shared__ u16 As[64 * 136];
  __shared__ u16 Bs[64 * 136];
  int tid = threadIdx.x;
  if (blockIdx.x < NBKT){
    int* h = (int*)As;               // 3 KB aliased into As
    kB_body(blockIdx.x, tid, pairs, bbase, off, deg, invdeg, cols,
            h, h + 256, h + 512);
  } else {
    const int rowBase = (blockIdx.x - NBKT) * 64;
    #pragma unroll
    for (int it = 0; it < 4; ++it){
      int chunk = tid + it * 256;
      int r = chunk >> 4, cseg = chunk & 15;
      int gr = rowBase + r;
      uint4 va = make_uint4(0u, 0u, 0u, 0u);
      if (gr < N_NODES) va = ((const uint4*)(A + (size_t)gr * 128))[cseg];
      ((uint4*)As)[r * 17 + cseg] = va;
    }
    __syncthreads();
    gemm_inner_lds(rowBase, tid, WT, bias, XLb, XR, 128, As, Bs);
  }
}

// ---------------- per-node aggregate (128-wide, relu, bf16 out as uint4) -------

__device__ __forceinline__ uint4 agg_node128(int node, int f,
                                             const int* __restrict__ off,
                                             const int* __restrict__ deg,
                                             const float* __restrict__ invdeg,
                                             const int* __restrict__ cols,
                                             const u16* __restrict__ XLb,
                                             const u16* __restrict__ XR){
  int start = off[node], cnt = deg[node];
  float inv = invdeg[node];
  const uint4* __restrict__ XR4 = (const uint4*)XR;   // row = 16 uint4
  const int* __restrict__ cb = cols + start;

  float2 a0 = make_float2(0.f, 0.f), a1 = a0, a2 = a0, a3 = a0;
  auto accum = [&](uint4 u){
    a0.x += lo_bf(u.x); a0.y += hi_bf(u.x);
    a1.x += lo_bf(u.y); a1.y += hi_bf(u.y);
    a2.x += lo_bf(u.z); a2.y += hi_bf(u.z);
    a3.x += lo_bf(u.w); a3.y += hi_bf(u.w);
  };

  int e = 0;
  int nfull = cnt & ~7;
  for (; e < nfull; e += 8){
    int s[8];
    #pragma unroll
    for (int j = 0; j < 8; ++j) s[j] = cb[e + j];
    uint4 u[8];
    #pragma unroll
    for (int j = 0; j < 8; ++j) u[j] = XR4[(size_t)s[j] * 16 + f];
    #pragma unroll
    for (int j = 0; j < 8; ++j) accum(u[j]);
  }
  if (e < cnt){                                 // masked 8-granule tail (<=1 iter)
    int last = cnt - 1;
    int s[8];
    #pragma unroll
    for (int j = 0; j < 8; ++j){
      int i = e + j;
      s[j] = cb[i < last ? i : last];
    }
    uint4 u[8];
    #pragma unroll
    for (int j = 0; j < 8; ++j) u[j] = XR4[(size_t)s[j] * 16 + f];
    #pragma unroll
    for (int j = 0; j < 8; ++j){
      if (e + j > last) u[j] = make_uint4(0u, 0u, 0u, 0u);
      accum(u[j]);
    }
  }

  uint4 xl = ((const uint4*)XLb)[(size_t)node * 16 + f];
  float o0 = lo_bf(xl.x) + inv * a0.x, o1 = hi_bf(xl.x) + inv * a0.y;
  float o2 = lo_bf(xl.y) + inv * a1.x, o3 = hi_bf(xl.y) + inv * a1.y;
  float o4 = lo_bf(xl.z) + inv * a2.x, o5 = hi_bf(xl.z) + inv * a2.y;
  float o6 = lo_bf(xl.w) + inv * a3.x, o7 = hi_bf(xl.w) + inv * a3.y;
  o0 = fmaxf(o0, 0.f); o1 = fmaxf(o1, 0.f); o2 = fmaxf(o2, 0.f); o3 = fmaxf(o3, 0.f);
  o4 = fmaxf(o4, 0.f); o5 = fmaxf(o5, 0.f); o6 = fmaxf(o6, 0.f); o7 = fmaxf(o7, 0.f);
  uint4 ov;
  ov.x = (unsigned)f2bf(o0) | ((unsigned)f2bf(o1) << 16);
  ov.y = (unsigned)f2bf(o2) | ((unsigned)f2bf(o3) << 16);
  ov.z = (unsigned)f2bf(o4) | ((unsigned)f2bf(o5) << 16);
  ov.w = (unsigned)f2bf(o6) | ((unsigned)f2bf(o7) << 16);
  return ov;
}

// ---------------- fused agg(layer l) + GEMM(layer l+1), 32-ROW TILES -----------
// 256 threads, grid 1563 (6.1 blocks/CU). LDS = 8.7K(As) + 17.4K(Bs) = 26.1 KB
// -> 6 blocks/CU resident (24 waves, 75% ceiling) vs R7's grid-capped 37.5%.
// Agg: 16 qwaves x 2 passes -> 32 rows. GEMM: 4 waves = wm(2 x 16-row) x wn(2).

__global__ __launch_bounds__(256, 6) void k_aggemm(const int* __restrict__ off,
                                                   const int* __restrict__ deg,
                                                   const float* __restrict__ invdeg,
                                                   const int* __restrict__ cols,
                                                   const u16* __restrict__ XLb_in,
                                                   const u16* __restrict__ XR_in,
                                                   const u16* __restrict__ WT,
                                                   const float* __restrict__ bias,
                                                   u16* __restrict__ XLb_out,
                                                   u16* __restrict__ XR_out,
                                                   int N1_out){
  __shared__ u16 As[32 * 136];       // 8.7 KB
  __shared__ u16 Bs[64 * 136];       // 17.4 KB
  int tid = threadIdx.x;
  int qq = tid >> 4, f = tid & 15;   // 16 quarter-waves
  int rowBase = blockIdx.x * 32;

  #pragma unroll
  for (int pass = 0; pass < 2; ++pass){
    int lr = pass * 16 + qq;                    // local row 0..31
    int node = rowBase + lr;
    uint4 ov = make_uint4(0u, 0u, 0u, 0u);
    if (node < N_NODES)
      ov = agg_node128(node, f, off, deg, invdeg, cols, XLb_in, XR_in);
    ((uint4*)As)[lr * 17 + f] = ov;
  }

  const int lane = tid & 63, wave = tid >> 6;
  const int quad = lane >> 4, l15 = lane & 15;
  const int wm = wave & 1, wn = wave >> 1;      // wm: 16-row half, wn: 32-col half
  const int nph = N1_out >> 5;                  // (2*N1)/64 phases (4 or 2)

  for (int p = 0; p < nph; ++p){
    int colBase = p * 64;
    #pragma unroll
    for (int it = 0; it < 4; ++it){
      int chunk = tid + it * 256;
      int r = chunk >> 4, cseg = chunk & 15;
      ((uint4*)Bs)[r * 17 + cseg] = ((const uint4*)(WT + (size_t)(colBase + r) * 128))[cseg];
    }
    __syncthreads();                            // also covers As readiness (p==0)

    v4f acc[2] = {};
    #pragma unroll
    for (int kt = 0; kt < 4; ++kt){
      int ko = kt * 32 + quad * 8;
      v8s a0 = *(const v8s*)&As[(wm * 16 + l15) * 136 + ko];
      v8s b0 = *(const v8s*)&Bs[(wn * 32 + l15) * 136 + ko];
      v8s b1 = *(const v8s*)&Bs[(wn * 32 + 16 + l15) * 136 + ko];
      acc[0] = __builtin_amdgcn_mfma_f32_16x16x32_bf16(a0, b0, acc[0], 0, 0, 0);
      acc[1] = __builtin_amdgcn_mfma_f32_16x16x32_bf16(a0, b1, acc[1], 0, 0, 0);
    }

    #pragma unroll
    for (int ni = 0; ni < 2; ++ni)
      #pragma unroll
      for (int r = 0; r < 4; ++r){
        int grow = rowBase + wm * 16 + quad * 4 + r;
        int gcol = colBase + wn * 32 + ni * 16 + l15;
        if (grow < N_NODES){
          float v = acc[ni][r];
          if (gcol < N1_out) XLb_out[(size_t)grow * N1_out + gcol] = f2bf(v + bias[gcol]);
          else               XR_out[(size_t)grow * N1_out + (gcol - N1_out)] = f2bf(v);
        }
      }
    __syncthreads();
  }
}

// ---------------- final aggregate (64-wide, fp32 out) --------------------------
__global__ __launch_bounds__(256) void k_agg64(const int* __restrict__ off,
                                               const int* __restrict__ deg,
                                               const float* __restrict__ invdeg,
                                               const int* __restrict__ cols,
                                               const u16* __restrict__ XLb,
                                               const u16* __restrict__ XR,
                                               float* __restrict__ out){
  int tid = threadIdx.x;
  int oo = tid >> 3, f = tid & 7;
  int node = blockIdx.x * 32 + oo;
  if (node >= N_NODES) return;
  int start = off[node], cnt = deg[node];
  float inv = invdeg[node];
  const uint4* __restrict__ XR4 = (const uint4*)XR;   // row = 8 uint4
  const int* __restrict__ cb = cols + start;

  float2 a0 = make_float2(0.f, 0.f), a1 = a0, a2 = a0, a3 = a0;
  auto accum = [&](uint4 u){
    a0.x += lo_bf(u.x); a0.y += hi_bf(u.x);
    a1.x += lo_bf(u.y); a1.y += hi_bf(u.y);
    a2.x += lo_bf(u.z); a2.y += hi_bf(u.z);
    a3.x += lo_bf(u.w); a3.y += hi_bf(u.w);
  };

  int e = 0;
  int nfull = cnt & ~7;
  for (; e < nfull; e += 8){
    int s[8];
    #pragma unroll
    for (int j = 0; j < 8; ++j) s[j] = cb[e + j];
    uint4 u[8];
    #pragma unroll
    for (int j = 0; j < 8; ++j) u[j] = XR4[(size_t)s[j] * 8 + f];
    #pragma unroll
    for (int j = 0; j < 8; ++j) accum(u[j]);
  }
  if (e < cnt){
    int last = cnt - 1;
    int s[8];
    #pragma unroll
    for (int j = 0; j < 8; ++j){
      int i = e + j;
      s[j] = cb[i < last ? i : last];
    }
    uint4 u[8];
    #pragma unroll
    for (int j = 0; j < 8; ++j) u[j] = XR4[(size_t)s[j] * 8 + f];
    #pragma unroll
    for (int j = 0; j < 8; ++j){
      if (e + j > last) u[j] = make_uint4(0u, 0u, 0u, 0u);
      accum(u[j]);
    }
  }

  uint4 xl = ((const uint4*)XLb)[(size_t)node * 8 + f];
  float4 oa, ob;
  oa.x = lo_bf(xl.x) + inv * a0.x; oa.y = hi_bf(xl.x) + inv * a0.y;
  oa.z = lo_bf(xl.y) + inv * a1.x; oa.w = hi_bf(xl.y) + inv * a1.y;
  ob.x = lo_bf(xl.z) + inv * a2.x; ob.y = hi_bf(xl.z) + inv * a2.y;
  ob.z = lo_bf(xl.w) + inv * a3.x; ob.w = hi_bf(xl.w) + inv * a3.y;
  ((float4*)out)[(size_t)node * 16 + 2 * f]     = oa;
  ((float4*)out)[(size_t)node * 16 + 2 * f + 1] = ob;
}

// ---------------- launch ----------------

extern "C" void kernel_launch(void* const* d_in, const int* in_sizes, int n_in,
                              void* d_out, int out_size, void* d_ws, size_t ws_size,
                              hipStream_t stream) {
  const float* x     = (const float*)d_in[0];
  const int*   edges = (const int*)  d_in[1];
  const float* Wl1 = (const float*)d_in[2];
  const float* Wr1 = (const float*)d_in[3];
  const float* b1  = (const float*)d_in[4];
  const float* Wl2 = (const float*)d_in[5];
  const float* Wr2 = (const float*)d_in[6];
  const float* b2  = (const float*)d_in[7];
  const float* Wl3 = (const float*)d_in[8];
  const float* Wr3 = (const float*)d_in[9];
  const float* b3  = (const float*)d_in[10];

  char* ws = (char*)d_ws;
  size_t o = 0;
  auto alloc = [&](size_t bytes) -> void* {
    void* p = ws + o;
    o += (bytes + 255) & ~(size_t)255;
    return p;
  };
  int*      deg    = (int*)     alloc(N_NODES * 4);
  int*      off    = (int*)     alloc(N_NODES * 4);
  float*    invdeg = (float*)   alloc(N_NODES * 4);
  int*      bpart  = (int*)     alloc((size_t)AB * NBKT * 4);
  int*      bbase  = (int*)     alloc((NBKT + 1) * 4);
  int*      bcur   = (int*)     alloc(NBKT * 4);
  unsigned* pairs  = (unsigned*)alloc((size_t)N_EDGES * 4);
  int*      cols   = (int*)     alloc(N_EDGES * 4);
  u16*      Xb     = (u16*)     alloc((size_t)N_NODES * 128 * 2);
  u16*      XLbA   = (u16*)     alloc((size_t)N_NODES * 128 * 2);
  u16*      XRbA   = (u16*)     alloc((size_t)N_NODES * 128 * 2);
  u16*      XLbB   = (u16*)     alloc((size_t)N_NODES * 128 * 2);
  u16*      XRbB   = (u16*)     alloc((size_t)N_NODES * 128 * 2);
  u16*      WT1    = (u16*)     alloc(256 * 128 * 2);
  u16*      WT2    = (u16*)     alloc(256 * 128 * 2);
  u16*      WT3    = (u16*)     alloc(128 * 128 * 2);

  // 1. prep (cast + wprep x3) + A1 partial histograms
  k_prep_a1<<<CASTB + 320 + AB, 256, 0, stream>>>(x, Xb, Wl1, Wr1, Wl2, Wr2,
                                                  Wl3, Wr3, WT1, WT2, WT3,
                                                  edges, bpart);
  // 2. reduce + scan bucket counts
  k_scanb<<<1, 256, 0, stream>>>(bpart, bbase, bcur);
  // 3. bucket-major pair scatter (packed u32 pairs)
  kA2<<<AB, 256, 0, stream>>>(edges, bcur, pairs);
  // 4. bucket counting sort (CSR) + layer-1 GEMM (Bs-staged, 64-row, R7 form)
  k_kb_gemm<<<NBKT + MG, 256, 0, stream>>>(pairs, bbase, off, deg, invdeg, cols,
                                           Xb, WT1, b1, XLbA, XRbA);
  // 5. agg1 + gemm2 fused, 32-row tiles
  k_aggemm<<<MG32, 256, 0, stream>>>(off, deg, invdeg, cols, XLbA, XRbA,
                                     WT2, b2, XLbB, XRbB, 128);
  // 6. agg2 + gemm3 fused
  k_aggemm<<<MG32, 256, 0, stream>>>(off, deg, invdeg, cols, XLbB, XRbB,
                                     WT3, b3, XLbA, XRbA, 64);
  // 7. final aggregate (fp32 out)
  k_agg64<<<(N_NODES + 31) / 32, 256, 0, stream>>>(off, deg, invdeg, cols,
                                                   XLbA, XRbA, (float*)d_out);
}